// Round 7
// baseline (67540.906 us; speedup 1.0000x reference)
//
#include <hip/hip_runtime.h>
#include <cstdint>

// DROP_MODE 3 = JAX partitionable threefry, bits = x0^x1  (VERIFIED r3+: absmax 0.0039)

static constexpr int TDEC = 400, TENC = 300, NMEL = 80, NBLK = 256;
static constexpr int RING = 32;

__device__ __forceinline__ uint2 threefry2x32(uint32_t k0, uint32_t k1,
                                              uint32_t x0, uint32_t x1) {
  uint32_t k2 = k0 ^ k1 ^ 0x1BD11BDAu;
  x0 += k0; x1 += k1;
#define TFR(r) { x0 += x1; x1 = (x1 << (r)) | (x1 >> (32 - (r))); x1 ^= x0; }
  TFR(13) TFR(15) TFR(26) TFR(6)
  x0 += k1; x1 += k2 + 1u;
  TFR(17) TFR(29) TFR(16) TFR(24)
  x0 += k2; x1 += k0 + 2u;
  TFR(13) TFR(15) TFR(26) TFR(6)
  x0 += k0; x1 += k1 + 3u;
  TFR(17) TFR(29) TFR(16) TFR(24)
  x0 += k1; x1 += k2 + 4u;
  TFR(13) TFR(15) TFR(26) TFR(6)
  x0 += k2; x1 += k0 + 5u;
#undef TFR
  return make_uint2(x0, x1);
}

__device__ __forceinline__ bool keep_mask(uint32_t key0, uint32_t key1, uint32_t idx) {
  uint2 o = threefry2x32(key0, key1, 0u, idx);
  uint32_t bits = o.x ^ o.y;
  float u = __uint_as_float((bits >> 9) | 0x3f800000u) - 1.0f;
  return u < 0.5f;
}

__device__ __forceinline__ float dot4(float4 w, float4 a) {
  return w.x * a.x + w.y * a.y + w.z * a.z + w.w * a.w;
}

__device__ __forceinline__ void s_rel(float* p, float v) {
  __hip_atomic_store(p, v, __ATOMIC_RELAXED, __HIP_MEMORY_SCOPE_AGENT);
}
__device__ __forceinline__ float l_rel(const float* p) {
  return __hip_atomic_load(p, __ATOMIC_RELAXED, __HIP_MEMORY_SCOPE_AGENT);
}

// ---- 16-member group barrier (group g = blocks g*16 .. g*16+15) -------------
__device__ __forceinline__ void rsync16(int* garr, int* grel, int g, int s, int val,
                                        bool inv) {
  __syncthreads();
  if (s == 0) {
    if (threadIdx.x < 15)
      while (__hip_atomic_load(&garr[(g * 16 + 1 + threadIdx.x) * 32], __ATOMIC_RELAXED,
                               __HIP_MEMORY_SCOPE_AGENT) < val)
        __builtin_amdgcn_s_sleep(2);
    __syncthreads();
    if (threadIdx.x == 0)
      __hip_atomic_store(&grel[g * 32], val, __ATOMIC_RELEASE, __HIP_MEMORY_SCOPE_AGENT);
  } else {
    if (threadIdx.x == 0) {
      __hip_atomic_store(&garr[(g * 16 + s) * 32], val, __ATOMIC_RELEASE,
                         __HIP_MEMORY_SCOPE_AGENT);
      while (__hip_atomic_load(&grel[g * 32], __ATOMIC_RELAXED,
                               __HIP_MEMORY_SCOPE_AGENT) < val)
        __builtin_amdgcn_s_sleep(2);
    }
  }
  if (inv && threadIdx.x == 0)  // periodic L1/L2 invalidate (ring hygiene)
    (void)__hip_atomic_load(&grel[g * 32], __ATOMIC_ACQUIRE, __HIP_MEMORY_SCOPE_AGENT);
  __syncthreads();
}

// ---- prenet (unchanged, verified) -------------------------------------------
template <int K>
__device__ __forceinline__ void prenet_layer(const float* in_lds, float* out_lds,
                                             float* out_g, const float* __restrict__ W,
                                             uint32_t key0, uint32_t key1, int b0) {
  const int tid = threadIdx.x;
  const int cgp = tid & 63, bg = tid >> 6;
  float acc[4][4];
#pragma unroll
  for (int cc = 0; cc < 4; ++cc)
#pragma unroll
    for (int rr = 0; rr < 4; ++rr) acc[cc][rr] = 0.f;
  const float4* W4 = (const float4*)W;
  const float4* in4 = (const float4*)in_lds;
  for (int k4 = 0; k4 < K / 4; ++k4) {
    float4 a[4];
#pragma unroll
    for (int rr = 0; rr < 4; ++rr) a[rr] = in4[(bg * 4 + rr) * (K / 4) + k4];
#pragma unroll
    for (int cc = 0; cc < 4; ++cc) {
      float4 w = W4[(cgp + 64 * cc) * (K / 4) + k4];
#pragma unroll
      for (int rr = 0; rr < 4; ++rr) acc[cc][rr] += dot4(w, a[rr]);
    }
  }
#pragma unroll
  for (int cc = 0; cc < 4; ++cc)
#pragma unroll
    for (int rr = 0; rr < 4; ++rr) {
      int c = cgp + 64 * cc, br = bg * 4 + rr;
      float val = fmaxf(acc[cc][rr], 0.f);
      val = keep_mask(key0, key1, (uint32_t)((b0 + br) * 256 + c)) ? val * 2.f : 0.f;
      if (out_lds) out_lds[br * 256 + c] = val;
      if (out_g) out_g[(b0 + br) * 256 + c] = val;
    }
  __syncthreads();
}

__global__ __launch_bounds__(256) void prenet_kernel(const float* __restrict__ mels,
                                                     const float* __restrict__ Wp0,
                                                     const float* __restrict__ Wp1,
                                                     const float* __restrict__ Wp2,
                                                     float* __restrict__ x_all) {
  __shared__ float bufA[16 * 256];
  __shared__ float bufB[16 * 256];
  const int t = blockIdx.x >> 1, b0 = (blockIdx.x & 1) * 16;
  const int tid = threadIdx.x;
  for (int i = tid; i < 16 * 80; i += 256) {
    int br = i / 80, k = i % 80;
    bufB[br * 80 + k] = (t == 0) ? 0.f : mels[((b0 + br) * TDEC + (t - 1)) * NMEL + k];
  }
  __syncthreads();
  uint2 k0v = threefry2x32(0u, 42u, 0u, (uint32_t)(t * 3 + 0));
  uint2 k1v = threefry2x32(0u, 42u, 0u, (uint32_t)(t * 3 + 1));
  uint2 k2v = threefry2x32(0u, 42u, 0u, (uint32_t)(t * 3 + 2));
  prenet_layer<80>(bufB, bufA, nullptr, Wp0, k0v.x, k0v.y, b0);
  prenet_layer<256>(bufA, bufB, nullptr, Wp1, k1v.x, k1v.y, b0);
  prenet_layer<256>(bufB, nullptr, x_all + t * 8192, Wp2, k2v.x, k2v.y, b0);
}

// ---- pmem = enc @ Wm.T (unchanged) ------------------------------------------
__global__ __launch_bounds__(256) void pmem_kernel(const float* __restrict__ enc,
                                                   const float* __restrict__ Wm,
                                                   float* __restrict__ pmem) {
  const int b = blockIdx.x / 10, pc = blockIdx.x % 10;
  const int j = threadIdx.x & 127, ph = threadIdx.x >> 7;
  const float4* Wm4 = (const float4*)Wm;
  const float4* enc4 = (const float4*)enc + (size_t)(b * 300 + pc * 30 + ph * 15) * 128;
  float acc[15];
#pragma unroll
  for (int pp = 0; pp < 15; ++pp) acc[pp] = 0.f;
  for (int k4 = 0; k4 < 128; ++k4) {
    float4 w = Wm4[j * 128 + k4];
#pragma unroll
    for (int pp = 0; pp < 15; ++pp) acc[pp] += dot4(w, enc4[pp * 128 + k4]);
  }
#pragma unroll
  for (int pp = 0; pp < 15; ++pp)
    pmem[(size_t)(b * 300 + pc * 30 + ph * 15 + pp) * 128 + j] = acc[pp];
}

// ---- persistent decoder: 16 groups x 16 slices, group-local sync only -------
struct DecParams {
  const float* enc; const float* xall; const float* pmem;
  const int* lens;
  const float *Wiha, *Whha, *biha, *bhha;
  const float *Wihd, *Whhd, *bihd, *bhhd;
  const float *Wq, *Kloc, *Wl, *vv, *Wout, *bout, *Wg, *bg;
  float *ah, *dh, *ctx, *e;
  int *garr, *grel;
  float *omel, *ogate, *oalign;
};

// LDS float offsets:
//   0..6655    scratch (S1 3584 | reduce 3584..6655; phase-D restage; phase3)
//   7000..8319 aw2 [2][330] float2
//   8320..10303 taps [32][31] float2
//   10304..11583 conv_l [2][32][20]
#define PAW 7000
#define PT2 8320
#define PCV 10304

__global__ __launch_bounds__(256) void decoder_kernel(DecParams P) {
  __shared__ float smem[11600];
  const int blk = blockIdx.x, tid = threadIdx.x;
  const int g = blk >> 4, s = blk & 15;
  const int r0 = 2 * g;
  float2* aw2 = (float2*)(smem + PAW);   // [ri][330], halo 15 each side
  float2* t2f = (float2*)(smem + PT2);
  float* conv_l = smem + PCV;            // [ri][32][20]
  const int pb = s * 19, pc = min(19, TENC - pb);
  int bno = 0;

  for (int i = tid; i < 660; i += 256) aw2[i] = make_float2(0.f, 0.f);
  for (int i = tid; i < 992; i += 256) {
    int f = i / 31, k = i % 31;
    t2f[i] = make_float2(P.Kloc[f * 62 + k], P.Kloc[f * 62 + 31 + k]);
  }
  __syncthreads();

  for (int tt = 0; tt <= TDEC; ++tt) {
    const int sc = tt & (RING - 1), s1 = (tt - 1) & (RING - 1), s2 = (tt - 2) & (RING - 1);
    float* ahC = P.ah + sc * 16384;
    const float* ahP = P.ah + s1 * 16384;
    const float* ctxP = P.ctx + s1 * 16384;
    float* dhW = P.dh + s1 * 16384;
    const float* dhP = P.dh + s2 * 16384;

    // ---- conv_t from LDS aw-state (t-1), block's position slice ----
    if (tt < TDEC) {
      int f = tid >> 3, po0 = tid & 7;
      for (int po = po0; po < pc; po += 8) {
        int p = pb + po;
        float a0 = 0.f, a1 = 0.f;
#pragma unroll
        for (int k = 0; k < 31; ++k) {
          float2 t = t2f[f * 31 + k];
          float2 v0 = aw2[p + k];
          float2 v1 = aw2[330 + p + k];
          a0 += v0.x * t.x + v0.y * t.y;
          a1 += v1.x * t.x + v1.y * t.y;
        }
        conv_l[(0 * 32 + f) * 20 + po] = a0;
        conv_l[(1 * 32 + f) * 20 + po] = a1;
      }
    }

    // ---- stage S1: x_t[2][256], ctx_{t-1}[2][512], ah_{t-1}[2][512], dh_{t-2}[2][512]
    float* xS = smem;
    float* cS = smem + 512;
    float* hS = smem + 1536;
    float* dS = smem + 2560;
    for (int i = tid; i < 512; i += 256) {
      int ri = i >> 8, k = i & 255;
      xS[i] = (tt < TDEC) ? P.xall[(size_t)tt * 8192 + (r0 + ri) * 256 + k] : 0.f;
    }
    for (int i = tid; i < 1024; i += 256) {
      int ri = i >> 9, k = i & 511;
      cS[i] = ctxP[(r0 + ri) * 512 + k];
      hS[i] = ahP[(r0 + ri) * 512 + k];
      dS[i] = dhP[(r0 + ri) * 512 + k];
    }
    __syncthreads();

    const float4* xS4 = (const float4*)xS;
    const float4* cS4 = (const float4*)cS;
    const float4* hS4 = (const float4*)hS;
    const float4* dS4 = (const float4*)dS;
    float* red = smem + 3584;  // [6][2][32][8] = 3072

    // ---- attGRU_t: slice [s*32, s*32+32), both rows ----
    if (tt < TDEC) {
      int ii = tid >> 3, ks = tid & 7;
      float acc[2][6] = {{0.f}};
      const float4* Wih4 = (const float4*)P.Wiha;
      const float4* Whh4 = (const float4*)P.Whha;
#pragma unroll
      for (int gate = 0; gate < 3; ++gate) {
        int wrow = gate * 512 + s * 32 + ii;
        const float4* wi = Wih4 + (size_t)wrow * 192;
        for (int k4 = ks * 24; k4 < ks * 24 + 24; ++k4) {
          float4 w = wi[k4];
          float4 a0 = (k4 < 64) ? xS4[k4] : cS4[k4 - 64];
          float4 a1 = (k4 < 64) ? xS4[64 + k4] : cS4[128 + (k4 - 64)];
          acc[0][gate] += dot4(w, a0);
          acc[1][gate] += dot4(w, a1);
        }
        const float4* wh = Whh4 + (size_t)wrow * 128;
        for (int k4 = ks * 16; k4 < ks * 16 + 16; ++k4) {
          float4 w = wh[k4];
          acc[0][3 + gate] += dot4(w, hS4[k4]);
          acc[1][3 + gate] += dot4(w, hS4[128 + k4]);
        }
      }
#pragma unroll
      for (int a = 0; a < 6; ++a)
#pragma unroll
        for (int ri = 0; ri < 2; ++ri)
          red[((a * 2 + ri) * 32 + ii) * 8 + ks] = acc[ri][a];
    }
    __syncthreads();
    if (tt < TDEC && tid < 64) {
      int ri = tid >> 5, ii = tid & 31, hi = s * 32 + ii;
      float gs[6];
#pragma unroll
      for (int a = 0; a < 6; ++a) {
        float sum = 0.f;
#pragma unroll
        for (int k = 0; k < 8; ++k) sum += red[((a * 2 + ri) * 32 + ii) * 8 + k];
        gs[a] = sum;
      }
      float gir = gs[0] + P.biha[hi], giz = gs[1] + P.biha[512 + hi], gin = gs[2] + P.biha[1024 + hi];
      float ghr = gs[3] + P.bhha[hi], ghz = gs[4] + P.bhha[512 + hi], ghn = gs[5] + P.bhha[1024 + hi];
      float rr = 1.f / (1.f + expf(-(gir + ghr)));
      float zz = 1.f / (1.f + expf(-(giz + ghz)));
      float nn = tanhf(gin + rr * ghn);
      float hp = hS[ri * 512 + hi];
      s_rel(&ahC[(r0 + ri) * 512 + hi], (1.f - zz) * nn + zz * hp);
    }
    __syncthreads();

    // ---- decGRU_{t-1}: input [ah_{t-1} | ctx_{t-1}], hprev dh_{t-2} ----
    if (tt >= 1) {
      int ii = tid >> 3, ks = tid & 7;
      float acc[2][6] = {{0.f}};
      const float4* Wih4 = (const float4*)P.Wihd;
      const float4* Whh4 = (const float4*)P.Whhd;
#pragma unroll
      for (int gate = 0; gate < 3; ++gate) {
        int wrow = gate * 512 + s * 32 + ii;
        const float4* wi = Wih4 + (size_t)wrow * 256;
        for (int k4 = ks * 32; k4 < ks * 32 + 32; ++k4) {
          float4 w = wi[k4];
          float4 a0 = (k4 < 128) ? hS4[k4] : cS4[k4 - 128];
          float4 a1 = (k4 < 128) ? hS4[128 + k4] : cS4[128 + (k4 - 128)];
          acc[0][gate] += dot4(w, a0);
          acc[1][gate] += dot4(w, a1);
        }
        const float4* wh = Whh4 + (size_t)wrow * 128;
        for (int k4 = ks * 16; k4 < ks * 16 + 16; ++k4) {
          float4 w = wh[k4];
          acc[0][3 + gate] += dot4(w, dS4[k4]);
          acc[1][3 + gate] += dot4(w, dS4[128 + k4]);
        }
      }
      __syncthreads();
#pragma unroll
      for (int a = 0; a < 6; ++a)
#pragma unroll
        for (int ri = 0; ri < 2; ++ri)
          red[((a * 2 + ri) * 32 + ii) * 8 + ks] = acc[ri][a];
    }
    __syncthreads();
    if (tt >= 1 && tid < 64) {
      int ri = tid >> 5, ii = tid & 31, hi = s * 32 + ii;
      float gs[6];
#pragma unroll
      for (int a = 0; a < 6; ++a) {
        float sum = 0.f;
#pragma unroll
        for (int k = 0; k < 8; ++k) sum += red[((a * 2 + ri) * 32 + ii) * 8 + k];
        gs[a] = sum;
      }
      float gir = gs[0] + P.bihd[hi], giz = gs[1] + P.bihd[512 + hi], gin = gs[2] + P.bihd[1024 + hi];
      float ghr = gs[3] + P.bhhd[hi], ghz = gs[4] + P.bhhd[512 + hi], ghn = gs[5] + P.bhhd[1024 + hi];
      float rr = 1.f / (1.f + expf(-(gir + ghr)));
      float zz = 1.f / (1.f + expf(-(giz + ghz)));
      float nn = tanhf(gin + rr * ghn);
      float hp = dS[ri * 512 + hi];
      s_rel(&dhW[(r0 + ri) * 512 + hi], (1.f - zz) * nn + zz * hp);
    }
    rsync16(P.garr, P.grel, g, s, ++bno, (tt & 15) == 0);  // SYNC1

    // ---- phase D: restage {ah_t, dh_{t-1}, ctx_{t-1}}; q-proj; outproj; energies
    {
      float* ahS = smem;          // [2][512]
      float* dS2 = smem + 1024;   // [2][512]
      float* cS2 = smem + 2048;   // [2][512]
      for (int i = tid; i < 1024; i += 256) {
        int ri = i >> 9, k = i & 511;
        ahS[i] = (tt < TDEC) ? ahC[(r0 + ri) * 512 + k] : 0.f;
        dS2[i] = dhW[(r0 + ri) * 512 + k];
        cS2[i] = ctxP[(r0 + ri) * 512 + k];
      }
      __syncthreads();
      float* qb = smem + 3584;    // [2][128]
      if (tt < TDEC) {
        int ri = tid >> 7, qi = tid & 127;
        const float4* Wq4 = (const float4*)P.Wq;
        const float4* a4 = (const float4*)ahS + ri * 128;
        float acc = 0.f;
        for (int k4 = 0; k4 < 128; ++k4) acc += dot4(Wq4[qi * 128 + k4], a4[k4]);
        qb[ri * 128 + qi] = acc;
      }
      float* op = smem + 3584 + 256;  // [96]
      if (tt >= 1) {  // outproj: m in {s, s+16, ..., 80}
        for (int u = tid; u < 96; u += 256) {
          int mi = u / 16, ri = (u >> 3) & 1, ks = u & 7;
          int m = s + 16 * mi;
          if (m <= 80) {
            const float4* W4 = (m < 80) ? ((const float4*)P.Wout + (size_t)m * 256)
                                        : (const float4*)P.Wg;
            const float4* dh4 = (const float4*)dS2 + ri * 128;
            const float4* cx4 = (const float4*)cS2 + ri * 128;
            float a = 0.f;
            for (int k4 = ks * 32; k4 < ks * 32 + 32; ++k4) {
              float4 x = (k4 < 128) ? dh4[k4] : cx4[k4 - 128];
              a += dot4(W4[k4], x);
            }
            op[u] = a;
          }
        }
      }
      __syncthreads();
      if (tt >= 1 && tid < 12) {
        int mi = tid >> 1, ri = tid & 1;
        int m = s + 16 * mi;
        if (m <= 80 && (m < 80 || s == 0)) {
          float sum = 0.f;
#pragma unroll
          for (int k = 0; k < 8; ++k) sum += op[((mi * 2 + ri) * 8) + k];
          int row = r0 + ri;
          if (m < 80) P.omel[(size_t)(row * 80 + m) * 400 + (tt - 1)] = sum + P.bout[m];
          else P.ogate[row * 400 + (tt - 1)] = sum + P.bg[0];
        }
      }
      if (tt < TDEC) {  // energies for block's position slice
        int w = tid >> 6, lane = tid & 63;
        int ri = w >> 1, row = r0 + ri;
        float wl0[32], wl1[32];
#pragma unroll
        for (int f = 0; f < 32; ++f) {
          wl0[f] = P.Wl[lane * 32 + f];
          wl1[f] = P.Wl[(lane + 64) * 32 + f];
        }
        float v0 = P.vv[lane], v1 = P.vv[lane + 64];
        float q0 = qb[ri * 128 + lane], q1 = qb[ri * 128 + 64 + lane];
        int len = P.lens[row];
        for (int po = (w & 1); po < pc; po += 2) {
          int p = pb + po;
          float a0 = 0.f, a1 = 0.f;
#pragma unroll
          for (int f = 0; f < 32; ++f) {
            float c = conv_l[(ri * 32 + f) * 20 + po];
            a0 += c * wl0[f];
            a1 += c * wl1[f];
          }
          float e0 = tanhf(q0 + P.pmem[((size_t)row * 300 + p) * 128 + lane] + a0) * v0;
          float e1 = tanhf(q1 + P.pmem[((size_t)row * 300 + p) * 128 + 64 + lane] + a1) * v1;
          float es = e0 + e1;
#pragma unroll
          for (int off = 32; off > 0; off >>= 1) es += __shfl_xor(es, off, 64);
          if (lane == 0) s_rel(&P.e[row * 300 + p], (p < len) ? es : -1e9f);
        }
      }
    }
    if (tt == TDEC) break;
    rsync16(P.garr, P.grel, g, s, ++bno, false);  // SYNC2

    // ---- phase 3: softmax (redundant per block) + aw update + ctx -----------
    {
      float* e_l = smem;  // [2][304]
      for (int i = tid; i < 600; i += 256) {
        int ri = i / 300, p = i - ri * 300;
        e_l[ri * 304 + p] = l_rel(&P.e[(r0 + ri) * 300 + p]);
      }
      __syncthreads();
      int w = tid >> 6, lane = tid & 63;
      if (w < 2) {
        int ri = w;
        float mx = -3.4e38f;
        for (int i = lane; i < 300; i += 64) mx = fmaxf(mx, e_l[ri * 304 + i]);
#pragma unroll
        for (int off = 32; off > 0; off >>= 1) mx = fmaxf(mx, __shfl_xor(mx, off, 64));
        float ls = 0.f;
        for (int i = lane; i < 300; i += 64) {
          float ex = expf(e_l[ri * 304 + i] - mx);
          e_l[ri * 304 + i] = ex;
          ls += ex;
        }
#pragma unroll
        for (int off = 32; off > 0; off >>= 1) ls += __shfl_xor(ls, off, 64);
        float inv = 1.f / ls;
        for (int i = lane; i < 300; i += 64) {
          float a = e_l[ri * 304 + i] * inv;
          float2 old = aw2[ri * 330 + 15 + i];
          aw2[ri * 330 + 15 + i] = make_float2(a, old.y + a);
          if (i >= pb && i < pb + pc)
            P.oalign[((size_t)((r0 + ri) * 400 + tt)) * 300 + i] = a;
        }
      }
      __syncthreads();
      float* cpart = smem + 1024;  // [64][4]
      {
        int out = tid & 63, ch = tid >> 6;
        int ri = out >> 5, col = s * 32 + (out & 31);
        int row = r0 + ri;
        float cp = 0.f;
        const float* eb = P.enc + ((size_t)row * 300) * 512 + col;
        for (int p = ch * 75; p < ch * 75 + 75; ++p)
          cp += aw2[ri * 330 + 15 + p].x * l_rel(eb + (size_t)p * 512);
        cpart[out * 4 + ch] = cp;
      }
      __syncthreads();
      if (tid < 64) {
        int ri = tid >> 5, col = s * 32 + (tid & 31);
        float* ctxC = P.ctx + sc * 16384;
        s_rel(&ctxC[(r0 + ri) * 512 + col],
              cpart[tid * 4] + cpart[tid * 4 + 1] + cpart[tid * 4 + 2] + cpart[tid * 4 + 3]);
      }
    }
    rsync16(P.garr, P.grel, g, s, ++bno, false);  // SYNC3
  }
}

// ---- host -------------------------------------------------------------------
extern "C" void kernel_launch(void* const* d_in, const int* in_sizes, int n_in,
                              void* d_out, int out_size, void* d_ws, size_t ws_size,
                              hipStream_t stream) {
  const float* enc = (const float*)d_in[0];
  const float* mels = (const float*)d_in[1];
  const int* lens = (const int*)d_in[2];
  const float* Wp0 = (const float*)d_in[3];
  const float* Wp1 = (const float*)d_in[4];
  const float* Wp2 = (const float*)d_in[5];
  const float* Wiha = (const float*)d_in[6];
  const float* Whha = (const float*)d_in[7];
  const float* biha = (const float*)d_in[8];
  const float* bhha = (const float*)d_in[9];
  const float* Wihd = (const float*)d_in[10];
  const float* Whhd = (const float*)d_in[11];
  const float* bihd = (const float*)d_in[12];
  const float* bhhd = (const float*)d_in[13];
  const float* Wq = (const float*)d_in[14];
  const float* Wm = (const float*)d_in[15];
  const float* Kloc = (const float*)d_in[16];
  const float* Wl = (const float*)d_in[17];
  const float* vv = (const float*)d_in[18];
  const float* Wout = (const float*)d_in[19];
  const float* bout = (const float*)d_in[20];
  const float* Wg = (const float*)d_in[21];
  const float* bg = (const float*)d_in[22];

  float* ws = (float*)d_ws;
  float* x_all = ws;                    // 3,276,800
  float* pmem = x_all + 3276800;        // 1,228,800
  float* ah = pmem + 1228800;           // ring32: 524,288
  float* dh = ah + 524288;              // 524,288
  float* ctx = dh + 524288;             // 524,288
  float* e = ctx + 524288;              // 9,600
  int* garr = (int*)(e + 9600);         // 8,192
  int* grel = garr + 8192;              // 512

  (void)hipMemsetAsync(ah + (RING - 1) * 16384, 0, 16384 * sizeof(float), stream);
  (void)hipMemsetAsync(dh + (RING - 1) * 16384, 0, 16384 * sizeof(float), stream);
  (void)hipMemsetAsync(dh + (RING - 2) * 16384, 0, 16384 * sizeof(float), stream);
  (void)hipMemsetAsync(ctx + (RING - 1) * 16384, 0, 16384 * sizeof(float), stream);
  (void)hipMemsetAsync(garr, 0, (8192 + 512) * sizeof(int), stream);

  prenet_kernel<<<800, 256, 0, stream>>>(mels, Wp0, Wp1, Wp2, x_all);
  pmem_kernel<<<320, 256, 0, stream>>>(enc, Wm, pmem);

  float* omel = (float*)d_out;                  // [32][80][400]
  float* ogate = omel + 32 * 80 * 400;          // [32][400]
  float* oalign = ogate + 32 * 400;             // [32][400][300]

  DecParams P;
  P.enc = enc; P.xall = x_all; P.pmem = pmem; P.lens = lens;
  P.Wiha = Wiha; P.Whha = Whha; P.biha = biha; P.bhha = bhha;
  P.Wihd = Wihd; P.Whhd = Whhd; P.bihd = bihd; P.bhhd = bhhd;
  P.Wq = Wq; P.Kloc = Kloc; P.Wl = Wl; P.vv = vv;
  P.Wout = Wout; P.bout = bout; P.Wg = Wg; P.bg = bg;
  P.ah = ah; P.dh = dh; P.ctx = ctx; P.e = e;
  P.garr = garr; P.grel = grel;
  P.omel = omel; P.ogate = ogate; P.oalign = oalign;

  decoder_kernel<<<NBLK, 256, 0, stream>>>(P);
}